// Round 1
// baseline (36.343 us; speedup 1.0000x reference)
//
#include <hip/hip_runtime.h>

// Problem constants (from reference):
//   x: [B=4, C=8, H=512, W=512] f32
//   BLOCK=(16,16), STRIDE=(8,8) -> nbh=nbw=63, NP=3969
//   out: [B, C, NP, 16, 16] f32
constexpr int H = 512, W = 512;
constexpr int BH = 16, BW = 16, SH = 8, SW = 8;
constexpr int NBH = (H - BH) / SH + 1;   // 63
constexpr int NBW = (W - BW) / SW + 1;   // 63
constexpr int NP  = NBH * NBW;           // 3969
constexpr int W4  = W / 4;               // 128 float4 per input row
constexpr int HW4 = H * W / 4;           // 65536 float4 per (b,c) image

__global__ void block_extract_kernel(const float4* __restrict__ x4,
                                     float4* __restrict__ out4,
                                     int total4) {
    int idx    = blockIdx.x * blockDim.x + threadIdx.x;
    int stride = gridDim.x * blockDim.x;
    for (int t = idx; t < total4; t += stride) {
        // out flat4 index t = ((bc*NP + p)*16 + i)*4 + q
        int q    = t & 3;          // float4 within patch row (j = 4q..4q+3)
        int i    = (t >> 2) & 15;  // patch row
        int rest = t >> 6;         // bc*NP + p
        int p    = rest % NP;
        int bc   = rest / NP;
        int pr   = p / NBW;
        int pc   = p - pr * NBW;
        int row  = pr * SH + i;
        // input col (floats) = pc*SW + 4q -> float4 index pc*2 + q (16B aligned)
        int in4  = bc * HW4 + row * W4 + pc * (SW / 4) + q;
        out4[t] = x4[in4];
    }
}

extern "C" void kernel_launch(void* const* d_in, const int* in_sizes, int n_in,
                              void* d_out, int out_size, void* d_ws, size_t ws_size,
                              hipStream_t stream) {
    const float* x = (const float*)d_in[0];
    float* out = (float*)d_out;

    int total4 = out_size / 4;  // 8,128,512 float4 stores
    int block  = 256;
    int grid   = 2048;          // 256 CU x 8 blocks/CU; grid-stride covers the rest

    block_extract_kernel<<<grid, block, 0, stream>>>(
        (const float4*)x, (float4*)out, total4);
}

// Round 3
// 28.451 us; speedup vs baseline: 1.2774x; 1.2774x over previous
//
#include <hip/hip_runtime.h>

// x: [B=4, C=8, H=512, W=512] f32 -> out: [B, C, 3969, 16, 16] f32
// BLOCK=(16,16), STRIDE=(8,8), nbh=nbw=63
constexpr int H = 512, W = 512;
constexpr int BH = 16, BW = 16, SH = 8, SW = 8;
constexpr int NBH = (H - BH) / SH + 1;   // 63
constexpr int NBW = (W - BW) / SW + 1;   // 63
constexpr int NP  = NBH * NBW;           // 3969
constexpr int W4  = W / 4;               // 128 float4 per input row
constexpr int HW4 = H * W / 4;           // 65536 float4 per (b,c) image
constexpr int BC      = 4 * 8;           // 32 (b,c) images
constexpr int NBLOCKS = BC * NBH;        // 2016 blocks, one per (bc, pr) strip
constexpr int CHUNK   = NBLOCKS / 8;     // 252 blocks per XCD (2016 % 8 == 0)
constexpr int S_STRIP = NBW * BH * (BW / 4); // 4032 float4 per strip

typedef float f32x4 __attribute__((ext_vector_type(4)));

__global__ __launch_bounds__(512) void block_extract_strip(
        const f32x4* __restrict__ x4, f32x4* __restrict__ out4) {
    int bid = blockIdx.x;
    // bijective XCD swizzle: consecutive swz (adjacent pr strips, shared rows)
    // land on the same XCD -> vertical-overlap reads hit that XCD's L2.
    int swz = (bid & 7) * CHUNK + (bid >> 3);
    int bc  = swz / NBH;              // one div per block (magic-mul)
    int pr  = swz - bc * NBH;

    const f32x4* __restrict__ src = x4 + bc * HW4 + pr * SH * W4;
    f32x4* __restrict__ dst = out4 + (size_t)(bc * NP + pr * NBW) * (BH * BW / 4);

    // s = pc*64 + i*4 + q  (matches output layout exactly -> dst[s])
    for (int s = threadIdx.x; s < S_STRIP; s += 512) {
        int q  = s & 3;          // float4 within patch row
        int i  = (s >> 2) & 15;  // patch row
        int pc = s >> 6;         // patch column 0..62
        f32x4 v = src[i * W4 + pc * (SW / 4) + q];
        __builtin_nontemporal_store(v, &dst[s]);
    }
}

extern "C" void kernel_launch(void* const* d_in, const int* in_sizes, int n_in,
                              void* d_out, int out_size, void* d_ws, size_t ws_size,
                              hipStream_t stream) {
    const f32x4* x4 = (const f32x4*)d_in[0];
    f32x4* out4 = (f32x4*)d_out;
    block_extract_strip<<<NBLOCKS, 512, 0, stream>>>(x4, out4);
}